// Round 1
// 962.971 us; speedup vs baseline: 1.0339x; 1.0339x over previous
//
#include <hip/hip_runtime.h>
#include <hip/hip_bf16.h>
#include <cstdint>
#include <cstddef>

// Problem constants
#define BDIM 8192
#define DDIM 1024
#define NCOL 16384          // 2*BDIM
#define TEMP_INV 20.0f      // 1/0.05
#define NT 16               // K-tiles of BK=64 (1024/64)

typedef __bf16 bf16;
typedef bf16 bf16x4 __attribute__((ext_vector_type(4)));
typedef bf16 bf16x8 __attribute__((ext_vector_type(8)));
typedef float f32x4 __attribute__((ext_vector_type(4)));
typedef int   i32x4 __attribute__((ext_vector_type(4)));

__device__ __forceinline__ void load_lds16(const void* g, void* l) {
    __builtin_amdgcn_global_load_lds(
        (const __attribute__((address_space(1))) void*)g,
        (__attribute__((address_space(3))) void*)l, 16, 0, 0);
}

__device__ __forceinline__ bf16x8 ds_read128(unsigned off) {
    i32x4 r;
    asm volatile("ds_read_b128 %0, %1" : "=v"(r) : "v"(off));
    return __builtin_bit_cast(bf16x8, r);
}

__device__ __forceinline__ unsigned lds_off(const void* p) {
    return (unsigned)(unsigned long long)(const __attribute__((address_space(3))) void*)p;
}

// ---------------------------------------------------------------------------
// Kernel 1: L2-normalize each row of P/E/C (fp32 in) -> bf16 out in workspace.
// Also zeroes rowsum[8192] (ws is poisoned 0xAA before every launch).
// ---------------------------------------------------------------------------
__global__ __launch_bounds__(256) void norm_kernel(
    const float* __restrict__ P, const float* __restrict__ E,
    const float* __restrict__ C,
    bf16* __restrict__ Pb, bf16* __restrict__ Eb, bf16* __restrict__ Cb,
    float* __restrict__ rowsum)
{
    int b = blockIdx.x;
    int which = b >> 13;       // 0:P 1:E 2:C
    int row = b & (BDIM - 1);
    const float* src = (which == 0) ? P : (which == 1 ? E : C);
    bf16* dst = (which == 0) ? Pb : (which == 1 ? Eb : Cb);
    src += (size_t)row * DDIM;
    dst += (size_t)row * DDIM;

    int t = threadIdx.x;
    if (b < 32) rowsum[b * 256 + t] = 0.0f;   // zero the 8192-entry accumulator

    float4 v = ((const float4*)src)[t];       // 256 threads * 4 = 1024 elems
    float ss = v.x * v.x + v.y * v.y + v.z * v.z + v.w * v.w;
    #pragma unroll
    for (int m = 32; m >= 1; m >>= 1) ss += __shfl_xor(ss, m, 64);

    __shared__ float wsum[4];
    if ((t & 63) == 0) wsum[t >> 6] = ss;
    __syncthreads();
    float tot = wsum[0] + wsum[1] + wsum[2] + wsum[3];
    float inv = 1.0f / fmaxf(sqrtf(tot), 1e-8f);

    bf16x4 o;
    o[0] = (bf16)(v.x * inv);
    o[1] = (bf16)(v.y * inv);
    o[2] = (bf16)(v.z * inv);
    o[3] = (bf16)(v.w * inv);
    ((bf16x4*)dst)[t] = o;
}

// ---------------------------------------------------------------------------
// Kernel 2: 256x256-tile, BK=64, 8-wave (2Mx4N), 8-phase pipelined bf16 GEMM
// (A * B^T) with fused scale + per-row sum(exp()) and nontemporal C-stores.
//
// LDS 128 KiB: A[2 buf][256][64] + B[2 buf][256][64] bf16.
// Swizzle (T2): lds_byte = tile_byte ^ (((tile_byte>>7)&7)<<4), applied via
// pre-swizzled GLOBAL source (linear global_load_lds dest) + swizzled ds_read.
// Schedule (T3+T4): 8 phases / 2 K-tiles; 1 half-tile (2 loads/thread) staged
// per phase; vmcnt(2) only at phases 4 and 8. T5: setprio around MFMA.
// T1: bijective XCD swizzle (2048 blocks % 8 == 0).
// ---------------------------------------------------------------------------
#define MIDBAR() do { __builtin_amdgcn_s_barrier(); \
    asm volatile("s_waitcnt lgkmcnt(0)" ::: "memory"); \
    __builtin_amdgcn_sched_barrier(0); \
    __builtin_amdgcn_s_setprio(1); } while (0)
#define ENDP() do { __builtin_amdgcn_s_setprio(0); \
    __builtin_amdgcn_s_barrier(); } while (0)
#define ENDPV(N) do { __builtin_amdgcn_s_setprio(0); \
    asm volatile("s_waitcnt vmcnt(" #N ")" ::: "memory"); \
    __builtin_amdgcn_s_barrier(); } while (0)

__global__ __launch_bounds__(512, 2) void gemm_kernel(
    const bf16* __restrict__ Pb, const bf16* __restrict__ Eb,
    const bf16* __restrict__ Cb,
    float* __restrict__ sims,        // row stride 16384 floats
    float* __restrict__ rowsum)
{
    __shared__ __align__(16) char smem[131072];   // A: [0,64K) B: [64K,128K)

    const int bid = blockIdx.x;
    const int sid = (bid & 7) * 256 + (bid >> 3); // XCD-aware swizzle (T1)
    const int ct = sid & 63;                      // col tile (0..63)
    const int rt = sid >> 6;                      // row tile (0..31)

    const char* Asrc = (const char*)Pb + (size_t)rt * 256 * 2048;
    const char* Bsrc = (const char*)((ct < 32) ? Eb : Cb)
                     + (size_t)(ct & 31) * 256 * 2048;

    const int t    = threadIdx.x;
    const int lane = t & 63;
    const int wave = t >> 6;
    const int wm   = wave >> 2;       // 0..1 : 128-row half
    const int wn   = wave & 3;        // 0..3 : 64-col slice
    const int q    = lane >> 4;
    const int l15  = lane & 15;
    const int c7   = l15 & 7;

    // Staging: pre-swizzled global source (LDS dest stays linear, rule 21).
    // L = u*8192 + t*16 (byte in 16KB half); T = L ^ (((L>>7)&7)<<4)
    const char* gAp[2]; const char* gBp[2];
    #pragma unroll
    for (int u = 0; u < 2; u++) {
        int L = u * 8192 + t * 16;
        int T = L ^ (((L >> 7) & 7) << 4);
        gAp[u] = Asrc + (size_t)(T >> 7) * 2048 + (T & 127);
        gBp[u] = Bsrc + (size_t)(T >> 7) * 2048 + (T & 127);
    }

    const unsigned LB    = lds_off(smem);
    const unsigned baseA = LB + (unsigned)(wm * 16384 + l15 * 128);
    const unsigned baseB = LB + 65536u
                         + (unsigned)((wn >> 1) * 16384 + ((wn & 1) * 64 + l15) * 128);
    const unsigned ck0   = (unsigned)((q ^ c7) << 4);  // swizzled 16B chunk, kk=0

    char* const ldst = smem + t * 16;
    auto stageA = [&](int buf, int half, int kt) {
        char* l = ldst + buf * 32768 + half * 16384;
        const char* g0 = gAp[0] + (size_t)half * 262144 + (size_t)kt * 128;
        const char* g1 = gAp[1] + (size_t)half * 262144 + (size_t)kt * 128;
        load_lds16(g0, l);
        load_lds16(g1, l + 8192);
    };
    auto stageB = [&](int buf, int half, int kt) {
        char* l = ldst + 65536 + buf * 32768 + half * 16384;
        const char* g0 = gBp[0] + (size_t)half * 262144 + (size_t)kt * 128;
        const char* g1 = gBp[1] + (size_t)half * 262144 + (size_t)kt * 128;
        load_lds16(g0, l);
        load_lds16(g1, l + 8192);
    };

    f32x4 acc[8][4];
    #pragma unroll
    for (int i = 0; i < 8; i++)
        #pragma unroll
        for (int j = 0; j < 4; j++) {
            f32x4 z = {0.f, 0.f, 0.f, 0.f};
            acc[i][j] = z;
        }

    bf16x8 af[4][2], bfr[2][2], bg[2][2];

    auto rdA = [&](bf16x8 (&d)[4][2], int buf, int ib) {
        unsigned base = baseA + (unsigned)buf * 32768u + (unsigned)ib * 2048u;
        #pragma unroll
        for (int ii = 0; ii < 4; ii++)
            #pragma unroll
            for (int kk = 0; kk < 2; kk++)
                d[ii][kk] = ds_read128(base + (unsigned)ii * 2048u + (ck0 ^ (kk << 6)));
    };
    auto rdB = [&](bf16x8 (&d)[2][2], int buf, int jb) {
        unsigned base = baseB + (unsigned)buf * 32768u + (unsigned)jb * 2048u;
        #pragma unroll
        for (int jj = 0; jj < 2; jj++)
            #pragma unroll
            for (int kk = 0; kk < 2; kk++)
                d[jj][kk] = ds_read128(base + (unsigned)jj * 2048u + (ck0 ^ (kk << 6)));
    };
    auto mm16 = [&](int ib, int jb, bf16x8 (&A)[4][2], bf16x8 (&Bv)[2][2]) {
        #pragma unroll
        for (int ii = 0; ii < 4; ii++)
            #pragma unroll
            for (int jj = 0; jj < 2; jj++)
                #pragma unroll
                for (int kk = 0; kk < 2; kk++)
                    acc[ib + ii][jb + jj] = __builtin_amdgcn_mfma_f32_16x16x32_bf16(
                        A[ii][kk], Bv[jj][kk], acc[ib + ii][jb + jj], 0, 0, 0);
    };

    // Prologue: K-tile 0 (buf0, 4 half-tiles) + A-h0 of K-tile 1 (buf1).
    stageA(0, 0, 0); stageA(0, 1, 0); stageB(0, 0, 0); stageB(0, 1, 0);
    stageA(1, 0, 1);
    asm volatile("s_waitcnt vmcnt(2)" ::: "memory");   // K-tile 0 landed
    __builtin_amdgcn_s_barrier();

    for (int m = 0; m < NT / 2; ++m) {
        const int k1 = 2 * m + 1, k2 = 2 * m + 2, k3 = 2 * m + 3;
        const bool st = (m < NT / 2 - 1);
        // ---- K-tile 2m (buf0) ----
        // P1: quadrant (i0-3, j0-1)
        rdA(af, 0, 0); rdB(bfr, 0, 0);
        stageA(1, 1, k1);
        MIDBAR(); mm16(0, 0, af, bfr); ENDP();
        // P2: (i0-3, j2-3)
        rdB(bg, 0, 2);
        stageB(1, 0, k1);
        MIDBAR(); mm16(0, 2, af, bg); ENDP();
        // P3: (i4-7, j2-3)
        rdA(af, 0, 4);
        stageB(1, 1, k1);
        MIDBAR(); mm16(4, 2, af, bg); ENDP();
        // P4: (i4-7, j0-1) — bfr held from P1; wait K-tile 2m+1 staged
        if (st) stageA(0, 0, k2);
        MIDBAR(); mm16(4, 0, af, bfr);
        if (st) { ENDPV(2); } else { ENDPV(0); }
        // ---- K-tile 2m+1 (buf1) ----
        // P5
        rdA(af, 1, 0); rdB(bfr, 1, 0);
        if (st) stageA(0, 1, k2);
        MIDBAR(); mm16(0, 0, af, bfr); ENDP();
        // P6
        rdB(bg, 1, 2);
        if (st) stageB(0, 0, k2);
        MIDBAR(); mm16(0, 2, af, bg); ENDP();
        // P7
        rdA(af, 1, 4);
        if (st) stageB(0, 1, k2);
        MIDBAR(); mm16(4, 2, af, bg); ENDP();
        // P8 — wait K-tile 2m+2 staged (leaves A-h0(2m+3) in flight)
        if (st) stageA(1, 0, k3);
        MIDBAR(); mm16(4, 0, af, bfr);
        ENDPV(2);
    }

    // Epilogue: C/D layout col=lane&15, row=quad*4+reg. Scale, nt-store,
    // fused per-row sum(exp()) -> atomicAdd into rowsum.
    const int gr0 = rt * 256 + wm * 128 + q * 4;
    const int gc0 = ct * 256 + wn * 64 + l15;
    #pragma unroll
    for (int i = 0; i < 8; i++) {
        #pragma unroll
        for (int r = 0; r < 4; r++) {
            const int grow = gr0 + i * 16 + r;
            float* orow = sims + (size_t)grow * NCOL;
            float rs = 0.f;
            #pragma unroll
            for (int j = 0; j < 4; j++) {
                float v = acc[i][j][r] * TEMP_INV;
                __builtin_nontemporal_store(v, orow + gc0 + j * 16);
                rs += __expf(v);
            }
            rs += __shfl_xor(rs, 1, 64);
            rs += __shfl_xor(rs, 2, 64);
            rs += __shfl_xor(rs, 4, 64);
            rs += __shfl_xor(rs, 8, 64);
            if (l15 == 0) atomicAdd(&rowsum[grow], rs);
        }
    }
}

// ---------------------------------------------------------------------------
// Kernel 3: loss = mean_i( log(rowsum[i]) - sims[i][i] )  -> d_out[0]
// ---------------------------------------------------------------------------
__global__ __launch_bounds__(1024) void finalize_kernel(
    const float* __restrict__ rowsum, const float* __restrict__ sims,
    float* __restrict__ out)
{
    int t = threadIdx.x;
    float s = 0.f;
    for (int i = t; i < BDIM; i += 1024) {
        float logz = logf(rowsum[i]);
        float tgt = sims[(size_t)i * NCOL + i];
        s += logz - tgt;
    }
    #pragma unroll
    for (int m = 32; m >= 1; m >>= 1) s += __shfl_xor(s, m, 64);
    __shared__ float ws[16];
    if ((t & 63) == 0) ws[t >> 6] = s;
    __syncthreads();
    if (t == 0) {
        float tot = 0.f;
        #pragma unroll
        for (int k = 0; k < 16; k++) tot += ws[k];
        out[0] = tot / (float)BDIM;
    }
}

// ---------------------------------------------------------------------------
extern "C" void kernel_launch(void* const* d_in, const int* in_sizes, int n_in,
                              void* d_out, int out_size, void* d_ws, size_t ws_size,
                              hipStream_t stream) {
    const float* P = (const float*)d_in[0];
    const float* E = (const float*)d_in[1];
    const float* C = (const float*)d_in[2];
    float* out = (float*)d_out;
    float* sims = out + 1;   // output 0 = loss scalar, then sims [8192,16384]

    constexpr size_t MAT_BYTES = (size_t)BDIM * DDIM * sizeof(bf16);  // 16 MB
    uint8_t* ws = (uint8_t*)d_ws;
    bf16* Pb = (bf16*)(ws);
    bf16* Eb = (bf16*)(ws + MAT_BYTES);
    bf16* Cb = (bf16*)(ws + 2 * MAT_BYTES);
    float* rowsum = (float*)(ws + 3 * MAT_BYTES);   // 8192 floats

    norm_kernel<<<3 * BDIM, 256, 0, stream>>>(P, E, C, Pb, Eb, Cb, rowsum);
    gemm_kernel<<<2048, 512, 0, stream>>>(Pb, Eb, Cb, sims, rowsum);
    finalize_kernel<<<1, 1024, 0, stream>>>(rowsum, sims, out);
}